// Round 2
// baseline (874.422 us; speedup 1.0000x reference)
//
#include <hip/hip_runtime.h>
#include <hip/hip_bf16.h>

#define NROWS 262144
#define NCLS 256
#define ALPHA 0.1f
#define EPSF 1e-8f

typedef __attribute__((ext_vector_type(8))) short bf16x8;
typedef __attribute__((ext_vector_type(4))) float f32x4;

static __device__ __forceinline__ short f2bf(float f) {
  union { float f; unsigned u; } v; v.f = f;
  unsigned r = (v.u + 0x7FFFu + ((v.u >> 16) & 1u)) >> 16;
  return (short)r;
}

// ---------------- K0: zero counters ----------------
__global__ void k_zero(unsigned* p) { p[threadIdx.x] = 0u; }

// ---------------- K1: label histogram (LDS-staged, 256 blocks) ----------------
__global__ __launch_bounds__(256) void k_count(const int* __restrict__ labels,
                                               unsigned* __restrict__ counts) {
  __shared__ unsigned h[NCLS];
  h[threadIdx.x] = 0u;
  __syncthreads();
  int base = blockIdx.x * 1024 + threadIdx.x;
#pragma unroll
  for (int i = 0; i < 4; ++i) atomicAdd(&h[labels[base + i * 256]], 1u);
  __syncthreads();
  unsigned v = h[threadIdx.x];
  if (v) atomicAdd(&counts[threadIdx.x], v);
}

// ---------------- K2: exclusive scan (256 values, trivial) ----------------
__global__ void k_scan(const unsigned* __restrict__ counts,
                       unsigned* __restrict__ offsets, unsigned* __restrict__ cursor) {
  if (threadIdx.x == 0) {
    unsigned acc = 0;
    for (int c = 0; c < NCLS; ++c) { offsets[c] = acc; cursor[c] = acc; acc += counts[c]; }
  }
}

// ---------------- K3: scatter row indices sorted by label ----------------
__global__ void k_scatter(const int* __restrict__ labels, unsigned* __restrict__ cursor,
                          unsigned* __restrict__ perm) {
  int i = blockIdx.x * blockDim.x + threadIdx.x;
  unsigned p = atomicAdd(&cursor[labels[i]], 1u);
  perm[p] = (unsigned)i;
}

// ---------------- K4: per-class mean (one block per class, 512 threads) ----------------
// Writes means in bf16 MFMA-B-fragment layout:
//   meansB[(((kt*16 + ct)*64) + lane)*8 + j]  <->  B[k=kt*32+(lane>>4)*8+j][col=ct*16+(lane&15)]
//   where B[k][c] = mean_c[k].  Also writes msq[c] = ||mean_c||^2 (fp32 means).
__global__ __launch_bounds__(512) void k_means2(
    const float* __restrict__ logits, const unsigned* __restrict__ counts,
    const unsigned* __restrict__ offsets, const unsigned* __restrict__ perm,
    short* __restrict__ meansB, float* __restrict__ msq) {
  __shared__ float part[512];
  __shared__ float meanbuf[256];
  int c = blockIdx.x;
  int t = threadIdx.x;
  int half = t >> 8;       // 0 or 1: which parity of row-indices this half-block sums
  int col  = t & 255;
  unsigned cnt = counts[c], off = offsets[c];

  float s0 = 0.f, s1 = 0.f;
  unsigned j = (unsigned)half;
  for (; j + 3 < cnt; j += 4) {       // two rows in flight per iteration
    unsigned r0 = perm[off + j];
    unsigned r1 = perm[off + j + 2];
    s0 += logits[r0 * 256u + (unsigned)col];
    s1 += logits[r1 * 256u + (unsigned)col];
  }
  for (; j < cnt; j += 2) s0 += logits[perm[off + j] * 256u + (unsigned)col];
  part[t] = s0 + s1;
  __syncthreads();

  if (t < 256) {
    float sum = part[t] + part[t + 256];
    meanbuf[t] = sum / ((float)cnt + EPSF);
  }
  __syncthreads();
  if (t < 256) part[t] = meanbuf[t] * meanbuf[t];
  __syncthreads();
  for (int s = 128; s > 0; s >>= 1) {   // tree-reduce 256 -> 1
    if (t < s) part[t] += part[t + s];
    __syncthreads();
  }
  if (t == 0) msq[c] = part[0];

  if (t < 256) {                        // t == k (mean element index)
    int kt = t >> 5;                    // k / 32
    int lh = (t >> 3) & 3;              // (k%32)/8
    int jj = t & 7;                     // k%8
    int lane = lh * 16 + (c & 15);
    int ct = c >> 4;
    meansB[(((kt * 16 + ct) * 64) + lane) * 8 + jj] = f2bf(meanbuf[t]);
  }
}

// ---------------- K5: fused softmax + MFMA GEMM + distance + normalize ----------------
// Softmax denominator cancels against the final normalization:
//   out_c = exp(x_c - rowmax - ALPHA*d_c) / sum_c exp(x_c - rowmax - ALPHA*d_c)
// Block: 1024 threads = 16 waves. Each wave owns 16 rows. Block tile = 256 rows.
// LDS: meansB (131072 B) | rowmax (256 f32) | rowxx (256 f32) | msq (256 f32)
#define SMEM_BYTES (131072 + 1024 + 1024 + 1024)

__global__ __launch_bounds__(1024) void k_main(
    const float* __restrict__ logits, const short* __restrict__ meansB_g,
    const float* __restrict__ msq_g, float* __restrict__ out) {
  extern __shared__ char smem[];
  short* meansB = (short*)smem;
  float* rowmax = (float*)(smem + 131072);
  float* rowxx  = (float*)(smem + 131072 + 1024);
  float* msq    = (float*)(smem + 131072 + 2048);

  int tid = threadIdx.x;
  // stage mean fragments: 131072 B = 8192 uint4
  {
    const uint4* src = (const uint4*)meansB_g;
    uint4* dst = (uint4*)meansB;
#pragma unroll
    for (int i = 0; i < 8; ++i) dst[tid + i * 1024] = src[tid + i * 1024];
    if (tid < 256) msq[tid] = msq_g[tid];
  }
  __syncthreads();

  int w   = tid >> 6;
  int l   = tid & 63;
  int l15 = l & 15;
  int lh  = l >> 4;

  // A-phase: lane l loads row (w*16 + l&15), k-chunk (l>>4)*8 per kt
  unsigned rowg = (unsigned)blockIdx.x * 256u + (unsigned)(w * 16 + l15);
  const float* rowptr = logits + (size_t)rowg * 256u;

  f32x4 acc[16];
#pragma unroll
  for (int ct = 0; ct < 16; ++ct) acc[ct] = (f32x4){0.f, 0.f, 0.f, 0.f};

  const bf16x8* mlds = (const bf16x8*)meansB;
  float mx = -3.4e38f, xx = 0.f;

#pragma unroll
  for (int kt = 0; kt < 8; ++kt) {
    int k0 = kt * 32 + lh * 8;
    f32x4 xa = *(const f32x4*)(rowptr + k0);
    f32x4 xb = *(const f32x4*)(rowptr + k0 + 4);
    bf16x8 af;
    af[0] = f2bf(xa[0]); af[1] = f2bf(xa[1]); af[2] = f2bf(xa[2]); af[3] = f2bf(xa[3]);
    af[4] = f2bf(xb[0]); af[5] = f2bf(xb[1]); af[6] = f2bf(xb[2]); af[7] = f2bf(xb[3]);
    mx = fmaxf(mx, fmaxf(fmaxf(xa[0], xa[1]), fmaxf(xa[2], xa[3])));
    mx = fmaxf(mx, fmaxf(fmaxf(xb[0], xb[1]), fmaxf(xb[2], xb[3])));
    xx += xa[0]*xa[0] + xa[1]*xa[1] + xa[2]*xa[2] + xa[3]*xa[3];
    xx += xb[0]*xb[0] + xb[1]*xb[1] + xb[2]*xb[2] + xb[3]*xb[3];
#pragma unroll
    for (int ct = 0; ct < 16; ++ct) {
      bf16x8 bfr = mlds[(kt * 16 + ct) * 64 + l];
      acc[ct] = __builtin_amdgcn_mfma_f32_16x16x32_bf16(af, bfr, acc[ct], 0, 0, 0);
    }
  }

  // combine row stats across the 4 lanes sharing a row (lanes l15+16*{0..3})
  mx = fmaxf(mx, __shfl_xor(mx, 16, 64));
  mx = fmaxf(mx, __shfl_xor(mx, 32, 64));
  xx = xx + __shfl_xor(xx, 16, 64);
  xx = xx + __shfl_xor(xx, 32, 64);
  if (l < 16) { rowmax[w * 16 + l15] = mx; rowxx[w * 16 + l15] = xx; }
  __syncthreads();

  // epilogue: D layout per 16x16 tile is row=(l>>4)*4+q, col=l&15
  float sums[4] = {0.f, 0.f, 0.f, 0.f};
  float rm[4], rx2[4];
#pragma unroll
  for (int q = 0; q < 4; ++q) {
    int rl = lh * 4 + q;
    rm[q]  = rowmax[w * 16 + rl];
    rx2[q] = rowxx[w * 16 + rl];
  }
  unsigned rowbase = (unsigned)blockIdx.x * 256u + (unsigned)(w * 16);

#pragma unroll
  for (int ct = 0; ct < 16; ++ct) {
    float mq = msq[ct * 16 + l15];
#pragma unroll
    for (int q = 0; q < 4; ++q) {
      int rl = lh * 4 + q;
      float x = logits[(size_t)(rowbase + rl) * 256u + (unsigned)(ct * 16 + l15)];
      float dot = acc[ct][q];
      float sq = rx2[q] + mq - 2.f * dot;
      float d = sqrtf(fmaxf(sq, 0.f));
      float g = __expf(x - rm[q] - ALPHA * d);
      acc[ct][q] = g;
      sums[q] += g;
    }
  }
#pragma unroll
  for (int q = 0; q < 4; ++q) {      // row-sum across the 16 lanes of this lh-group
    sums[q] += __shfl_xor(sums[q], 1, 64);
    sums[q] += __shfl_xor(sums[q], 2, 64);
    sums[q] += __shfl_xor(sums[q], 4, 64);
    sums[q] += __shfl_xor(sums[q], 8, 64);
    sums[q] = 1.f / sums[q];
  }
#pragma unroll
  for (int ct = 0; ct < 16; ++ct) {
#pragma unroll
    for (int q = 0; q < 4; ++q) {
      int rl = lh * 4 + q;
      __builtin_nontemporal_store(acc[ct][q] * sums[q],
          &out[(size_t)(rowbase + rl) * 256u + (unsigned)(ct * 16 + l15)]);
    }
  }
}

// ---------------- host launcher ----------------
extern "C" void kernel_launch(void* const* d_in, const int* in_sizes, int n_in,
                              void* d_out, int out_size, void* d_ws, size_t ws_size,
                              hipStream_t stream) {
  const float* logits = (const float*)d_in[0];
  const int*   labels = (const int*)d_in[1];
  float* out = (float*)d_out;

  char* ws = (char*)d_ws;
  unsigned* counts  = (unsigned*)ws;            // 256 u32
  unsigned* offsets = counts + 256;             // 256 u32
  unsigned* cursor  = offsets + 256;            // 256 u32
  float*    msq     = (float*)(ws + 4096);      // 256 f32
  short*    meansB  = (short*)(ws + 8192);      // 65536 bf16 = 131072 B
  unsigned* perm    = (unsigned*)(ws + 8192 + 131072); // 262144 u32 = 1 MiB

  // Not a stream op; idempotent and graph-capture-safe. No static guard
  // (harness forbids call-count-dependent behavior).
  hipFuncSetAttribute(reinterpret_cast<const void*>(k_main),
                      hipFuncAttributeMaxDynamicSharedMemorySize, SMEM_BYTES);

  k_zero<<<1, 768, 0, stream>>>(counts);  // zeroes counts+offsets+cursor (contiguous)
  k_count<<<NROWS / 1024, 256, 0, stream>>>(labels, counts);
  k_scan<<<1, 64, 0, stream>>>(counts, offsets, cursor);
  k_scatter<<<NROWS / 256, 256, 0, stream>>>(labels, cursor, perm);
  k_means2<<<NCLS, 512, 0, stream>>>(logits, counts, offsets, perm, meansB, msq);
  k_main<<<NROWS / 256, 1024, SMEM_BYTES, stream>>>(logits, meansB, msq, out);
}

// Round 5
// 571.887 us; speedup vs baseline: 1.5290x; 1.5290x over previous
//
#include <hip/hip_runtime.h>
#include <hip/hip_bf16.h>

#define NROWS 262144
#define NCLS 256
#define ALPHA 0.1f
#define EPSF 1e-8f
#define S_SPLIT 8

typedef __attribute__((ext_vector_type(8))) short bf16x8;
typedef __attribute__((ext_vector_type(4))) float f32x4;

static __device__ __forceinline__ short f2bf(float f) {
  union { float f; unsigned u; } v; v.f = f;
  unsigned r = (v.u + 0x7FFFu + ((v.u >> 16) & 1u)) >> 16;
  return (short)r;
}

// ---------------- K0: zero counters + class-sum accumulators ----------------
// Zero region: counts[256] | offsets[256] | cursor[256] | sums[65536] (u32/f32)
#define ZERO_WORDS (768 + 65536)
__global__ __launch_bounds__(256) void k_zero(unsigned* p) {
  int i = blockIdx.x * 256 + threadIdx.x;
  if (i < ZERO_WORDS) p[i] = 0u;
}

// ---------------- K1: label histogram (LDS-staged, 256 blocks) ----------------
__global__ __launch_bounds__(256) void k_count(const int* __restrict__ labels,
                                               unsigned* __restrict__ counts) {
  __shared__ unsigned h[NCLS];
  h[threadIdx.x] = 0u;
  __syncthreads();
  int base = blockIdx.x * 1024 + threadIdx.x;
#pragma unroll
  for (int i = 0; i < 4; ++i) atomicAdd(&h[labels[base + i * 256]], 1u);
  __syncthreads();
  unsigned v = h[threadIdx.x];
  if (v) atomicAdd(&counts[threadIdx.x], v);
}

// ---------------- K2: parallel exclusive scan (256 values) ----------------
__global__ __launch_bounds__(256) void k_scan(const unsigned* __restrict__ counts,
                                              unsigned* __restrict__ offsets,
                                              unsigned* __restrict__ cursor) {
  __shared__ unsigned buf[NCLS];
  int t = threadIdx.x;
  unsigned v = counts[t];
  buf[t] = v;
  __syncthreads();
  for (int d = 1; d < NCLS; d <<= 1) {
    unsigned x = (t >= d) ? buf[t - d] : 0u;
    __syncthreads();
    buf[t] += x;
    __syncthreads();
  }
  unsigned excl = buf[t] - v;
  offsets[t] = excl;
  cursor[t] = excl;
}

// ---------------- K3: block-staged scatter (65536 global atomics total) ----------------
__global__ __launch_bounds__(256) void k_scatter(const int* __restrict__ labels,
                                                 unsigned* __restrict__ cursor,
                                                 unsigned* __restrict__ perm) {
  __shared__ unsigned hist[NCLS];
  __shared__ unsigned base[NCLS];
  int t = threadIdx.x;
  int b0 = blockIdx.x * 1024;
  hist[t] = 0u;
  __syncthreads();
  int lbl[4];
#pragma unroll
  for (int i = 0; i < 4; ++i) {
    lbl[i] = labels[b0 + t + i * 256];
    atomicAdd(&hist[lbl[i]], 1u);
  }
  __syncthreads();
  unsigned h = hist[t];
  base[t] = h ? atomicAdd(&cursor[t], h) : 0u;
  __syncthreads();
  hist[t] = 0u;
  __syncthreads();
#pragma unroll
  for (int i = 0; i < 4; ++i) {
    unsigned pos = base[lbl[i]] + atomicAdd(&hist[lbl[i]], 1u);
    perm[pos] = (unsigned)(b0 + t + i * 256);
  }
}

// ---------------- K4a: per-class partial sums (8 blocks per class) ----------------
// Block (c,s): rows perm[off + s + S_SPLIT*i], 4 rows in flight; one col per thread.
__global__ __launch_bounds__(256) void k_partial(
    const float* __restrict__ logits, const unsigned* __restrict__ counts,
    const unsigned* __restrict__ offsets, const unsigned* __restrict__ perm,
    float* __restrict__ sums) {
  int c = blockIdx.x;
  int s = blockIdx.y;
  int t = threadIdx.x;
  unsigned cnt = counts[c], off = offsets[c];

  float a0 = 0.f, a1 = 0.f, a2 = 0.f, a3 = 0.f;
  unsigned j = (unsigned)s;
  for (; j + 3u * S_SPLIT < cnt; j += 4u * S_SPLIT) {
    unsigned r0 = perm[off + j];
    unsigned r1 = perm[off + j + S_SPLIT];
    unsigned r2 = perm[off + j + 2u * S_SPLIT];
    unsigned r3 = perm[off + j + 3u * S_SPLIT];
    a0 += logits[(size_t)r0 * 256u + (unsigned)t];
    a1 += logits[(size_t)r1 * 256u + (unsigned)t];
    a2 += logits[(size_t)r2 * 256u + (unsigned)t];
    a3 += logits[(size_t)r3 * 256u + (unsigned)t];
  }
  for (; j < cnt; j += S_SPLIT) a0 += logits[(size_t)perm[off + j] * 256u + (unsigned)t];
  float a = (a0 + a1) + (a2 + a3);
  if (a != 0.f) atomicAdd(&sums[c * 256 + t], a);
}

// ---------------- K4b: finalize — mean, ||mean||^2, bf16 B-fragment layout ----------------
// meansB[(((kt*16 + ct)*64) + lane)*8 + j]  <->  B[k=kt*32+(lane>>4)*8+j][col=ct*16+(lane&15)]
__global__ __launch_bounds__(256) void k_finalize(
    const float* __restrict__ sums, const unsigned* __restrict__ counts,
    short* __restrict__ meansB, float* __restrict__ msq) {
  __shared__ float red[NCLS];
  int c = blockIdx.x;
  int t = threadIdx.x;           // t == k (mean element index)
  float mean = sums[c * 256 + t] / ((float)counts[c] + EPSF);
  red[t] = mean * mean;
  __syncthreads();
  for (int st = 128; st > 0; st >>= 1) {
    if (t < st) red[t] += red[t + st];
    __syncthreads();
  }
  if (t == 0) msq[c] = red[0];

  int kt = t >> 5;
  int lh = (t >> 3) & 3;
  int jj = t & 7;
  int lane = lh * 16 + (c & 15);
  int ct = c >> 4;
  meansB[(((kt * 16 + ct) * 64) + lane) * 8 + jj] = f2bf(mean);
}

// ---------------- K5: fused softmax + MFMA GEMM + distance + normalize ----------------
// Softmax denominator cancels against the final normalization:
//   out_c = exp(x_c - rowmax - ALPHA*d_c) / sum_c exp(x_c - rowmax - ALPHA*d_c)
// Block: 1024 threads = 16 waves. Each wave owns 16 rows. Block tile = 256 rows.
#define SMEM_BYTES (131072 + 1024 + 1024 + 1024)

__global__ __launch_bounds__(1024) void k_main(
    const float* __restrict__ logits, const short* __restrict__ meansB_g,
    const float* __restrict__ msq_g, float* __restrict__ out) {
  extern __shared__ char smem[];
  short* meansB = (short*)smem;
  float* rowmax = (float*)(smem + 131072);
  float* rowxx  = (float*)(smem + 131072 + 1024);
  float* msq    = (float*)(smem + 131072 + 2048);

  int tid = threadIdx.x;
  {
    const uint4* src = (const uint4*)meansB_g;
    uint4* dst = (uint4*)meansB;
#pragma unroll
    for (int i = 0; i < 8; ++i) dst[tid + i * 1024] = src[tid + i * 1024];
    if (tid < 256) msq[tid] = msq_g[tid];
  }
  __syncthreads();

  int w   = tid >> 6;
  int l   = tid & 63;
  int l15 = l & 15;
  int lh  = l >> 4;

  unsigned rowg = (unsigned)blockIdx.x * 256u + (unsigned)(w * 16 + l15);
  const float* rowptr = logits + (size_t)rowg * 256u;

  f32x4 acc[16];
#pragma unroll
  for (int ct = 0; ct < 16; ++ct) acc[ct] = (f32x4){0.f, 0.f, 0.f, 0.f};

  const bf16x8* mlds = (const bf16x8*)meansB;
  float mx = -3.4e38f, xx = 0.f;

#pragma unroll
  for (int kt = 0; kt < 8; ++kt) {
    int k0 = kt * 32 + lh * 8;
    f32x4 xa = *(const f32x4*)(rowptr + k0);
    f32x4 xb = *(const f32x4*)(rowptr + k0 + 4);
    bf16x8 af;
    af[0] = f2bf(xa[0]); af[1] = f2bf(xa[1]); af[2] = f2bf(xa[2]); af[3] = f2bf(xa[3]);
    af[4] = f2bf(xb[0]); af[5] = f2bf(xb[1]); af[6] = f2bf(xb[2]); af[7] = f2bf(xb[3]);
    mx = fmaxf(mx, fmaxf(fmaxf(xa[0], xa[1]), fmaxf(xa[2], xa[3])));
    mx = fmaxf(mx, fmaxf(fmaxf(xb[0], xb[1]), fmaxf(xb[2], xb[3])));
    xx += xa[0]*xa[0] + xa[1]*xa[1] + xa[2]*xa[2] + xa[3]*xa[3];
    xx += xb[0]*xb[0] + xb[1]*xb[1] + xb[2]*xb[2] + xb[3]*xb[3];
#pragma unroll
    for (int ct = 0; ct < 16; ++ct) {
      bf16x8 bfr = mlds[(kt * 16 + ct) * 64 + l];
      acc[ct] = __builtin_amdgcn_mfma_f32_16x16x32_bf16(af, bfr, acc[ct], 0, 0, 0);
    }
  }

  mx = fmaxf(mx, __shfl_xor(mx, 16, 64));
  mx = fmaxf(mx, __shfl_xor(mx, 32, 64));
  xx = xx + __shfl_xor(xx, 16, 64);
  xx = xx + __shfl_xor(xx, 32, 64);
  if (l < 16) { rowmax[w * 16 + l15] = mx; rowxx[w * 16 + l15] = xx; }
  __syncthreads();

  float sums[4] = {0.f, 0.f, 0.f, 0.f};
  float rm[4], rx2[4];
#pragma unroll
  for (int q = 0; q < 4; ++q) {
    int rl = lh * 4 + q;
    rm[q]  = rowmax[w * 16 + rl];
    rx2[q] = rowxx[w * 16 + rl];
  }
  unsigned rowbase = (unsigned)blockIdx.x * 256u + (unsigned)(w * 16);

#pragma unroll
  for (int ct = 0; ct < 16; ++ct) {
    float mq = msq[ct * 16 + l15];
#pragma unroll
    for (int q = 0; q < 4; ++q) {
      int rl = lh * 4 + q;
      float x = logits[(size_t)(rowbase + rl) * 256u + (unsigned)(ct * 16 + l15)];
      float dot = acc[ct][q];
      float sq = rx2[q] + mq - 2.f * dot;
      float d = sqrtf(fmaxf(sq, 0.f));
      float g = __expf(x - rm[q] - ALPHA * d);
      acc[ct][q] = g;
      sums[q] += g;
    }
  }
#pragma unroll
  for (int q = 0; q < 4; ++q) {
    sums[q] += __shfl_xor(sums[q], 1, 64);
    sums[q] += __shfl_xor(sums[q], 2, 64);
    sums[q] += __shfl_xor(sums[q], 4, 64);
    sums[q] += __shfl_xor(sums[q], 8, 64);
    sums[q] = 1.f / sums[q];
  }
#pragma unroll
  for (int ct = 0; ct < 16; ++ct) {
#pragma unroll
    for (int q = 0; q < 4; ++q) {
      int rl = lh * 4 + q;
      __builtin_nontemporal_store(acc[ct][q] * sums[q],
          &out[(size_t)(rowbase + rl) * 256u + (unsigned)(ct * 16 + l15)]);
    }
  }
}

// ---------------- host launcher ----------------
extern "C" void kernel_launch(void* const* d_in, const int* in_sizes, int n_in,
                              void* d_out, int out_size, void* d_ws, size_t ws_size,
                              hipStream_t stream) {
  const float* logits = (const float*)d_in[0];
  const int*   labels = (const int*)d_in[1];
  float* out = (float*)d_out;

  char* ws = (char*)d_ws;
  // Zeroed region (contiguous): counts | offsets | cursor | sums
  unsigned* counts  = (unsigned*)ws;                    // 256 u32
  unsigned* offsets = counts + 256;                     // 256 u32
  unsigned* cursor  = offsets + 256;                    // 256 u32
  float*    sums    = (float*)(cursor + 256);           // 65536 f32 (256 KiB)
  float*    msq     = (float*)(ws + 266240);            // 256 f32
  short*    meansB  = (short*)(ws + 267264);            // 65536 bf16 (128 KiB), 16B-aligned
  unsigned* perm    = (unsigned*)(ws + 267264 + 131072);// 262144 u32 (1 MiB)

  hipFuncSetAttribute(reinterpret_cast<const void*>(k_main),
                      hipFuncAttributeMaxDynamicSharedMemorySize, SMEM_BYTES);

  k_zero<<<(ZERO_WORDS + 255) / 256, 256, 0, stream>>>(counts);
  k_count<<<NROWS / 1024, 256, 0, stream>>>(labels, counts);
  k_scan<<<1, 256, 0, stream>>>(counts, offsets, cursor);
  k_scatter<<<NROWS / 1024, 256, 0, stream>>>(labels, cursor, perm);
  k_partial<<<dim3(NCLS, S_SPLIT), 256, 0, stream>>>(logits, counts, offsets, perm, sums);
  k_finalize<<<NCLS, 256, 0, stream>>>(sums, counts, meansB, msq);
  k_main<<<NROWS / 256, 1024, SMEM_BYTES, stream>>>(logits, meansB, msq, out);
}